// Round 7
// baseline (409.804 us; speedup 1.0000x reference)
//
#include <hip/hip_runtime.h>

#define NB 288          // 32 query + 256 poi batches
#define NBQ 32
#define NBP 256
#define LTOK 16
#define CIN 8192
#define H1 256
#define H2 32
#define MASKW 256       // 8192 bits / 32
#define XROW 264        // padded LDS row stride (bf16 elems)

typedef __attribute__((ext_vector_type(8))) short short8;   // 8 bf16 = 4 VGPRs
typedef __attribute__((ext_vector_type(4))) float f32x4;

__device__ __forceinline__ unsigned short f2bf(float f) {
    unsigned u = __float_as_uint(f);
    u += 0x7fffu + ((u >> 16) & 1u);
    return (unsigned short)(u >> 16);
}
__device__ __forceinline__ float bf2f(unsigned short u) {
    return __uint_as_float(((unsigned)u) << 16);
}

// ---------------- fused prep: enc_w transpose-pack, conv-w prep, w3 pack,
// ---------------- zero masks/Cmat + wtp sentinel row ----------------------
__global__ __launch_bounds__(256) void k_prep(const float* __restrict__ encw,
                                              const float* __restrict__ w1,
                                              const float* __restrict__ w2,
                                              const float* __restrict__ w3c,
                                              const float* __restrict__ dw3,
                                              unsigned* __restrict__ wtp,
                                              unsigned short* __restrict__ wtb,
                                              unsigned* __restrict__ w3p,
                                              unsigned* __restrict__ masks,
                                              float* __restrict__ Cmat) {
    int g = blockIdx.x, tid = threadIdx.x;
    if (g < 2048) {
        // enc_w (256,8192) fp32 -> wtp[k][pair] packed 2xbf16
        __shared__ float tile[32][33];
        int k0 = (g >> 3) * 32, h0 = (g & 7) * 32;
        int tx = tid & 31, ty = tid >> 5;
#pragma unroll
        for (int i = 0; i < 32; i += 8)
            tile[ty + i][tx] = encw[(h0 + ty + i) * CIN + k0 + tx];
        __syncthreads();
        int kl = tid >> 3, pw = tid & 7;
#pragma unroll
        for (int u = 0; u < 2; ++u) {
            int p = pw + u * 8;
            unsigned lo = f2bf(tile[2 * p][kl]);
            unsigned hi = f2bf(tile[2 * p + 1][kl]);
            wtp[(size_t)(k0 + kl) * 128 + (h0 >> 1) + p] = (hi << 16) | lo;
        }
    } else if (g < 5888) {
        // conv weights w[o][i][d] fp32 -> WT bf16 [l][o][d][i]
        int bx = g - 2048;
        int l = bx / 1280;
        int r = bx - l * 1280;
        int o = r / 5;
        int d = r - o * 5;
        const float* w = (l == 0) ? w1 : (l == 1) ? w2 : w3c;
        wtb[(size_t)l * 327680 + (size_t)o * 1280 + d * 256 + tid] =
            f2bf(w[(size_t)o * 1280 + tid * 5 + d]);
    } else if (g < 6400) {
        // dec_w3 (8192 x 32) fp32 -> w3p[k][16] packed bf16 pairs
        int idx = (g - 5888) * 256 + tid;
        int k = idx >> 4, pw = idx & 15;
        unsigned lo = f2bf(dw3[k * 32 + 2 * pw]);
        unsigned hi = f2bf(dw3[k * 32 + 2 * pw + 1]);
        w3p[idx] = (hi << 16) | lo;
    } else {
        int b = g - 6400;                 // 0..287
        masks[b * MASKW + tid] = 0u;
        if (tid < 32) Cmat[b * 32 + tid] = 0.f;
        if (b == 0 && tid < 128) wtp[(size_t)8192 * 128 + tid] = 0u;  // sentinel
    }
}

// ---------------- fused scan + gather: one block per (batch,token) row ----
__global__ __launch_bounds__(256) void k_scanG(const float* __restrict__ qx,
                                               const float* __restrict__ px,
                                               const unsigned* __restrict__ wtp,
                                               unsigned* __restrict__ masks,
                                               unsigned* __restrict__ xbufu) {
    int row = blockIdx.x;              // 0..4607
    int b = row >> 4;
    const float* x = (b < NBQ) ? (qx + (size_t)row * CIN)
                               : (px + (size_t)(row - NBQ * LTOK) * CIN);
    __shared__ int idxs[200];
    __shared__ int cnt;
    __shared__ float sL[2][128], sH[2][128];
    int tid = threadIdx.x;
    if (tid == 0) cnt = 0;
    __syncthreads();
    const float4* x4 = (const float4*)x;
    float4 r[8];
#pragma unroll
    for (int j = 0; j < 8; ++j) r[j] = x4[j * 256 + tid];   // 8 outstanding loads
#pragma unroll
    for (int j = 0; j < 8; ++j) {
        unsigned ox = __float_as_uint(r[j].x) | __float_as_uint(r[j].y) |
                      __float_as_uint(r[j].z) | __float_as_uint(r[j].w);
        if (ox) {
            int base = (j * 256 + tid) * 4;
            float vv[4] = {r[j].x, r[j].y, r[j].z, r[j].w};
#pragma unroll
            for (int c = 0; c < 4; ++c) {
                if (vv[c] != 0.f) {
                    int k = base + c;
                    int p = atomicAdd(&cnt, 1);
                    if (p < 192) idxs[p] = k;
                    atomicOr(&masks[b * MASKW + (k >> 5)], 1u << (k & 31));
                }
            }
        }
    }
    __syncthreads();
    int n = min(cnt, 192);
    for (int i = n + tid; i < 200; i += 256) idxs[i] = 8192;   // sentinel pad
    __syncthreads();
    // gather: 128 channel-pairs x 2 j-halves
    int pair = tid & 127, half = tid >> 7;
    float aL = 0.f, aH = 0.f;
    for (int j0 = 0; j0 < n; j0 += 8) {
        int4 ia = *(const int4*)(idxs + j0 + half * 4);
        int id[4] = {ia.x, ia.y, ia.z, ia.w};
#pragma unroll
        for (int u = 0; u < 4; ++u) {
            unsigned v = wtp[(size_t)id[u] * 128 + pair];
            aL += __uint_as_float(v << 16);
            aH += __uint_as_float(v & 0xffff0000u);
        }
    }
    sL[half][pair] = aL; sH[half][pair] = aH;
    __syncthreads();
    if (tid < 128) {
        float L = sL[0][tid] + sL[1][tid];
        float H = sH[0][tid] + sH[1][tid];
        unsigned bl = f2bf(L), bh = f2bf(H);
        xbufu[(size_t)row * 128 + tid] = (bh << 16) | bl;
    }
}

// ---------------- conv layer GEMM (layers 1,2): 32 rows x 32 outs ---------
__global__ __launch_bounds__(256) void k_cgemm(const unsigned short* __restrict__ actIn,
                                               unsigned short* __restrict__ actOut,
                                               const unsigned short* __restrict__ wl,
                                               const float* __restrict__ bias) {
    __shared__ unsigned short Als[2 * 20 * XROW];   // 21.1 KB
    __shared__ unsigned short Bls[32 * XROW];       // 16.9 KB
    int tid = threadIdx.x;
    int m0 = blockIdx.x * 32, n0 = blockIdx.y * 32;

    int* Ai = (int*)Als;
#pragma unroll
    for (int i = tid; i < 20 * XROW; i += 256) Ai[i] = 0;
    __syncthreads();

    int row = tid >> 3, part = tid & 7;
    {
        const short8* src = (const short8*)(actIn + (size_t)(m0 + row) * 256 + part * 32);
        unsigned short* dst = Als + ((row >> 4) * 20 + (row & 15) + 2) * XROW + part * 32;
#pragma unroll
        for (int j = 0; j < 4; ++j) *(short8*)(dst + j * 8) = src[j];
    }
    const unsigned short* bsrc = wl + (size_t)(n0 + row) * 1280 + part * 32;
    short8 rb[4];
#pragma unroll
    for (int j = 0; j < 4; ++j) rb[j] = *(const short8*)(bsrc + j * 8);

    int lane = tid & 63, wave = tid >> 6;
    int lane15 = lane & 15, quad = lane >> 4;
    int wm = wave & 1, wn = wave >> 1;
    unsigned short* bdst = Bls + row * XROW + part * 32;

    f32x4 acc = (f32x4){0.f, 0.f, 0.f, 0.f};
#pragma unroll 1
    for (int d = 0; d < 5; ++d) {
#pragma unroll
        for (int j = 0; j < 4; ++j) *(short8*)(bdst + j * 8) = rb[j];
        __syncthreads();
        if (d < 4) {
            const unsigned short* s2 = bsrc + (d + 1) * 256;
#pragma unroll
            for (int j = 0; j < 4; ++j) rb[j] = *(const short8*)(s2 + j * 8);
        }
        const unsigned short* ap = Als + (wm * 20 + lane15 + d) * XROW + quad * 8;
        const unsigned short* bp = Bls + (wn * 16 + lane15) * XROW + quad * 8;
#pragma unroll
        for (int kk = 0; kk < 8; ++kk) {
            short8 av = *(const short8*)(ap + kk * 32);
            short8 bv = *(const short8*)(bp + kk * 32);
            acc = __builtin_amdgcn_mfma_f32_16x16x32_bf16(av, bv, acc, 0, 0, 0);
        }
        __syncthreads();
    }

    int o = n0 + wn * 16 + lane15;
    float bv = bias[o];
    int rbase = m0 + wm * 16 + quad * 4;
#pragma unroll
    for (int r = 0; r < 4; ++r)
        actOut[(size_t)(rbase + r) * 256 + o] = f2bf(fmaxf(acc[r] + bv, 0.f));
}

// ---------------- conv layer 3 + fused mean/residual/relu + dec_w1 matvec --
__global__ __launch_bounds__(256) void k_cgemm3(const unsigned short* __restrict__ actIn,
                                                const unsigned short* __restrict__ wl,
                                                const float* __restrict__ bias,
                                                const unsigned short* __restrict__ xbuf,
                                                const float* __restrict__ dw1,
                                                float* __restrict__ Cmat) {
    __shared__ unsigned short Als[2 * 20 * XROW];
    __shared__ unsigned short Bls[32 * XROW];
    __shared__ float els[2][32];
    int tid = threadIdx.x;
    int m0 = blockIdx.x * 32, n0 = blockIdx.y * 32;

    int* Ai = (int*)Als;
#pragma unroll
    for (int i = tid; i < 20 * XROW; i += 256) Ai[i] = 0;
    __syncthreads();

    int row = tid >> 3, part = tid & 7;
    {
        const short8* src = (const short8*)(actIn + (size_t)(m0 + row) * 256 + part * 32);
        unsigned short* dst = Als + ((row >> 4) * 20 + (row & 15) + 2) * XROW + part * 32;
#pragma unroll
        for (int j = 0; j < 4; ++j) *(short8*)(dst + j * 8) = src[j];
    }
    const unsigned short* bsrc = wl + (size_t)(n0 + row) * 1280 + part * 32;
    short8 rb[4];
#pragma unroll
    for (int j = 0; j < 4; ++j) rb[j] = *(const short8*)(bsrc + j * 8);

    int lane = tid & 63, wave = tid >> 6;
    int lane15 = lane & 15, quad = lane >> 4;
    int wm = wave & 1, wn = wave >> 1;
    unsigned short* bdst = Bls + row * XROW + part * 32;

    f32x4 acc = (f32x4){0.f, 0.f, 0.f, 0.f};
#pragma unroll 1
    for (int d = 0; d < 5; ++d) {
#pragma unroll
        for (int j = 0; j < 4; ++j) *(short8*)(bdst + j * 8) = rb[j];
        __syncthreads();
        if (d < 4) {
            const unsigned short* s2 = bsrc + (d + 1) * 256;
#pragma unroll
            for (int j = 0; j < 4; ++j) rb[j] = *(const short8*)(s2 + j * 8);
        }
        const unsigned short* ap = Als + (wm * 20 + lane15 + d) * XROW + quad * 8;
        const unsigned short* bp = Bls + (wn * 16 + lane15) * XROW + quad * 8;
#pragma unroll
        for (int kk = 0; kk < 8; ++kk) {
            short8 av = *(const short8*)(ap + kk * 32);
            short8 bv = *(const short8*)(bp + kk * 32);
            acc = __builtin_amdgcn_mfma_f32_16x16x32_bf16(av, bv, acc, 0, 0, 0);
        }
        __syncthreads();
    }

    // token-mean of relu(conv3) + residual mean + relu -> e tile (2 batches x 32 outs)
    int o_l = wn * 16 + lane15;
    int o = n0 + o_l;
    float bv = bias[o];
    float sf = 0.f;
#pragma unroll
    for (int r = 0; r < 4; ++r) sf += fmaxf(acc[r] + bv, 0.f);
    sf += __shfl_xor(sf, 16, 64);
    sf += __shfl_xor(sf, 32, 64);
    if (quad == 0) {
        int bb = 2 * blockIdx.x + wm;
        float rs = 0.f;                 // residual: sum of 16 token row-sums from xbuf
#pragma unroll
        for (int t = 0; t < 16; ++t)
            rs += bf2f(xbuf[((size_t)bb * 16 + t) * 256 + o]);
        els[wm][o_l] = fmaxf((sf + rs) * (1.f / 16.f), 0.f);
    }
    __syncthreads();
    // partial Cmat[b][o'] += sum_{o in tile} dec_w1[o'][off + o] * e[b][o]
    if (tid < 64) {
        int b2 = tid >> 5, op = tid & 31;
        int bb = 2 * blockIdx.x + b2;
        const float* wr = dw1 + (size_t)op * 512 + (bb < NBQ ? 0 : 256) + n0;
        float s = 0.f;
#pragma unroll
        for (int j = 0; j < 32; ++j) s = fmaf(wr[j], els[b2][j], s);
        atomicAdd(&Cmat[bb * 32 + op], s);
    }
}

// ---------------- per-(q,p): tiny MLP + compacted sparse decode -----------
__global__ __launch_bounds__(256) void k_pair(const float* __restrict__ Cmat,
                                              const float* __restrict__ b1,
                                              const float* __restrict__ w2,
                                              const float* __restrict__ b2,
                                              const unsigned* __restrict__ w3p,
                                              const unsigned* __restrict__ masks,
                                              float* __restrict__ desc) {
    int p = blockIdx.x, q = blockIdx.y;
    __shared__ float h1[32];
    __shared__ __align__(16) float h2s[32];
    __shared__ int idxs[3072];
    __shared__ int cnt;
    __shared__ float wsum[4], wq[4];
    int tid = threadIdx.x;
    if (tid == 0) cnt = 0;
    __syncthreads();
    unsigned mq = masks[q * MASKW + tid];
    unsigned m = mq & masks[(NBQ + p) * MASKW + tid];
    int nb = __popc(m);
    if (nb) {
        int pos = atomicAdd(&cnt, nb);
        while (m) {
            int bit = __ffs(m) - 1;
            m &= m - 1;
            idxs[pos++] = tid * 32 + bit;
        }
    }
    if (tid < 32)
        h1[tid] = fmaxf(Cmat[q * 32 + tid] + Cmat[(NBQ + p) * 32 + tid] + b1[tid], 0.f);
    __syncthreads();
    if (tid < 32) {
        float s = b2[tid];
#pragma unroll
        for (int j = 0; j < 32; ++j) s = fmaf(w2[tid * 32 + j], h1[j], s);
        h2s[tid] = fmaxf(s, 0.f);
    }
    __syncthreads();
    int n = cnt;
    int rowi = tid >> 2, part = tid & 3;          // 64 rows/iter, 4 lanes/row
    float h2v[8];
#pragma unroll
    for (int j = 0; j < 8; ++j) h2v[j] = h2s[part * 8 + j];
    float local = 0.f;
    for (int base = 0; base < n; base += 64) {
        int r = base + rowi;
        bool act = r < n;
        float dot = 0.f;
        if (act) {
            uint4 wv = *(const uint4*)(w3p + (size_t)idxs[r] * 16 + part * 4);
            unsigned wu[4] = {wv.x, wv.y, wv.z, wv.w};
#pragma unroll
            for (int u = 0; u < 4; ++u) {
                dot += __uint_as_float(wu[u] << 16) * h2v[2 * u];
                dot += __uint_as_float(wu[u] & 0xffff0000u) * h2v[2 * u + 1];
            }
        }
        dot += __shfl_xor(dot, 1);
        dot += __shfl_xor(dot, 2);
        if (act && part == 0)
            local += 1.f + (dot >= 0.f ? dot : dot * 0.125f);
    }
    float qcf = (float)__popc(mq);
#pragma unroll
    for (int st = 1; st < 64; st <<= 1) {
        local += __shfl_xor(local, st);
        qcf   += __shfl_xor(qcf, st);
    }
    if ((tid & 63) == 0) { wsum[tid >> 6] = local; wq[tid >> 6] = qcf; }
    __syncthreads();
    if (tid == 0) {
        float t  = wsum[0] + wsum[1] + wsum[2] + wsum[3];
        float qb = wq[0] + wq[1] + wq[2] + wq[3];
        desc[q * 256 + p] = t / qb;
    }
}

// ---------------- per-q: normalize over p + geo fusion --------------------
__global__ __launch_bounds__(256) void k_final(const float* __restrict__ desc,
                                               const float* __restrict__ qloc,
                                               const float* __restrict__ ploc,
                                               const float* __restrict__ sa,
                                               const float* __restrict__ sb,
                                               const float* __restrict__ sc,
                                               const float* __restrict__ sd,
                                               float* __restrict__ out) {
    __shared__ float red[256];
    int q = blockIdx.x, tid = threadIdx.x;
    float v = desc[q * 256 + tid];
    red[tid] = v; __syncthreads();
    for (int st = 128; st > 0; st >>= 1) {
        if (tid < st) red[tid] += red[tid + st];
        __syncthreads();
    }
    float mean = red[0] * (1.f / 256.f);
    __syncthreads();
    float dv = v - mean;
    red[tid] = dv * dv; __syncthreads();
    for (int st = 128; st > 0; st >>= 1) {
        if (tid < st) red[tid] += red[tid + st];
        __syncthreads();
    }
    float var = red[0] * (1.f / 255.f);
    float norm = dv / (sqrtf(var) + 1e-6f);
    float dx = qloc[q * 2]     - ploc[tid * 2];
    float dy = qloc[q * 2 + 1] - ploc[tid * 2 + 1];
    float dist = sqrtf(dx * dx + dy * dy);
    float z = sa[0] * norm + sb[0];
    float sig = 1.f / (1.f + expf(-z));
    out[q * 256 + tid] = (sc[0] - sig) * (-logf(dist + 1.f) - sd[0]);
}

extern "C" void kernel_launch(void* const* d_in, const int* in_sizes, int n_in,
                              void* d_out, int out_size, void* d_ws, size_t ws_size,
                              hipStream_t stream) {
    const float* qx   = (const float*)d_in[0];
    const float* qloc = (const float*)d_in[1];
    const float* px   = (const float*)d_in[2];
    const float* ploc = (const float*)d_in[3];
    const float* encw = (const float*)d_in[4];
    const float* cw1  = (const float*)d_in[5];
    const float* cb1  = (const float*)d_in[6];
    const float* cw2  = (const float*)d_in[7];
    const float* cb2  = (const float*)d_in[8];
    const float* cw3  = (const float*)d_in[9];
    const float* cb3  = (const float*)d_in[10];
    const float* dw1  = (const float*)d_in[11];
    const float* db1  = (const float*)d_in[12];
    const float* dw2  = (const float*)d_in[13];
    const float* db2  = (const float*)d_in[14];
    const float* dw3  = (const float*)d_in[15];
    const float* sa   = (const float*)d_in[16];
    const float* sb   = (const float*)d_in[17];
    const float* sc   = (const float*)d_in[18];
    const float* sd   = (const float*)d_in[19];

    char* w = (char*)d_ws;
    unsigned*       wtp   = (unsigned*)w;       w += (size_t)8193 * 128 * 4;      // 4.19 MB
    unsigned short* xbuf  = (unsigned short*)w; w += (size_t)NB * LTOK * H1 * 2;  // 2.25 MB
    unsigned short* act1  = (unsigned short*)w; w += (size_t)NB * LTOK * H1 * 2;
    unsigned short* act2  = (unsigned short*)w; w += (size_t)NB * LTOK * H1 * 2;
    unsigned short* wtb   = (unsigned short*)w; w += (size_t)3 * 256 * 1280 * 2;  // 1.97 MB
    unsigned*       w3p   = (unsigned*)w;       w += (size_t)CIN * 16 * 4;        // 512 KB
    float*          Cmat  = (float*)w;          w += (size_t)NB * H2 * 4;
    unsigned*       masks = (unsigned*)w;       w += (size_t)NB * MASKW * 4;
    float*          desc  = (float*)w;          w += (size_t)NBQ * NBP * 4;

    // MEASUREMENT PROBE ROUND: each idempotent kernel launched twice so
    // (a) new_total - 335 = T_prep + T_scanG + T_pair + T_final exactly,
    // (b) any kernel > ~77 us becomes visible in rocprof top-5.
    // Conv chain (known: 52 us) launched once. Numerics unchanged.
    k_prep<<<6688, 256, 0, stream>>>(encw, cw1, cw2, cw3, dw3,
                                     wtp, wtb, w3p, masks, Cmat);
    k_prep<<<6688, 256, 0, stream>>>(encw, cw1, cw2, cw3, dw3,
                                     wtp, wtb, w3p, masks, Cmat);
    k_scanG<<<NB * LTOK, 256, 0, stream>>>(qx, px, wtp, masks, (unsigned*)xbuf);
    k_scanG<<<NB * LTOK, 256, 0, stream>>>(qx, px, wtp, masks, (unsigned*)xbuf);
    dim3 cgrid(NB * LTOK / 32, 8);
    k_cgemm<<<cgrid, 256, 0, stream>>>(xbuf, act1, wtb,          cb1);
    k_cgemm<<<cgrid, 256, 0, stream>>>(act1, act2, wtb + 327680, cb2);
    k_cgemm3<<<cgrid, 256, 0, stream>>>(act2, wtb + 2 * 327680, cb3, xbuf, dw1, Cmat);
    k_pair<<<dim3(NBP, NBQ), 256, 0, stream>>>(Cmat, db1, dw2, db2, w3p, masks, desc);
    k_pair<<<dim3(NBP, NBQ), 256, 0, stream>>>(Cmat, db1, dw2, db2, w3p, masks, desc);
    k_final<<<NBQ, 256, 0, stream>>>(desc, qloc, ploc, sa, sb, sc, sd, (float*)d_out);
    k_final<<<NBQ, 256, 0, stream>>>(desc, qloc, ploc, sa, sb, sc, sd, (float*)d_out);
}

// Round 8
// 326.653 us; speedup vs baseline: 1.2546x; 1.2546x over previous
//
#include <hip/hip_runtime.h>

#define NB 288          // 32 query + 256 poi batches
#define NBQ 32
#define NBP 256
#define LTOK 16
#define CIN 8192
#define H1 256
#define H2 32
#define MASKW 256       // 8192 bits / 32
#define XROW 264        // padded LDS row stride (bf16 elems)

typedef __attribute__((ext_vector_type(8))) short short8;   // 8 bf16 = 4 VGPRs
typedef __attribute__((ext_vector_type(4))) float f32x4;

__device__ __forceinline__ unsigned short f2bf(float f) {
    unsigned u = __float_as_uint(f);
    u += 0x7fffu + ((u >> 16) & 1u);
    return (unsigned short)(u >> 16);
}
__device__ __forceinline__ float bf2f(unsigned short u) {
    return __uint_as_float(((unsigned)u) << 16);
}

// ---------------- fused prep: enc_w transpose-pack, conv-w prep, w3 pack,
// ---------------- zero masks/Cmat + wtp sentinel row ----------------------
__global__ __launch_bounds__(256) void k_prep(const float* __restrict__ encw,
                                              const float* __restrict__ w1,
                                              const float* __restrict__ w2,
                                              const float* __restrict__ w3c,
                                              const float* __restrict__ dw3,
                                              unsigned* __restrict__ wtp,
                                              unsigned short* __restrict__ wtb,
                                              unsigned* __restrict__ w3p,
                                              unsigned* __restrict__ masks,
                                              float* __restrict__ Cmat) {
    int g = blockIdx.x, tid = threadIdx.x;
    if (g < 2048) {
        // enc_w (256,8192) fp32 -> wtp[k][pair] packed 2xbf16
        __shared__ float tile[32][33];
        int k0 = (g >> 3) * 32, h0 = (g & 7) * 32;
        int tx = tid & 31, ty = tid >> 5;
#pragma unroll
        for (int i = 0; i < 32; i += 8)
            tile[ty + i][tx] = encw[(h0 + ty + i) * CIN + k0 + tx];
        __syncthreads();
        int kl = tid >> 3, pw = tid & 7;
#pragma unroll
        for (int u = 0; u < 2; ++u) {
            int p = pw + u * 8;
            unsigned lo = f2bf(tile[2 * p][kl]);
            unsigned hi = f2bf(tile[2 * p + 1][kl]);
            wtp[(size_t)(k0 + kl) * 128 + (h0 >> 1) + p] = (hi << 16) | lo;
        }
    } else if (g < 5888) {
        // conv weights w[o][i][d] fp32 -> WT bf16 [l][o][d][i]
        int bx = g - 2048;
        int l = bx / 1280;
        int r = bx - l * 1280;
        int o = r / 5;
        int d = r - o * 5;
        const float* w = (l == 0) ? w1 : (l == 1) ? w2 : w3c;
        wtb[(size_t)l * 327680 + (size_t)o * 1280 + d * 256 + tid] =
            f2bf(w[(size_t)o * 1280 + tid * 5 + d]);
    } else if (g < 6400) {
        // dec_w3 (8192 x 32) fp32 -> w3p[k][16] packed bf16 pairs
        int idx = (g - 5888) * 256 + tid;
        int k = idx >> 4, pw = idx & 15;
        unsigned lo = f2bf(dw3[k * 32 + 2 * pw]);
        unsigned hi = f2bf(dw3[k * 32 + 2 * pw + 1]);
        w3p[idx] = (hi << 16) | lo;
    } else {
        int b = g - 6400;                 // 0..287
        masks[b * MASKW + tid] = 0u;
        if (tid < 32) Cmat[b * 32 + tid] = 0.f;
        if (b == 0 && tid < 128) wtp[(size_t)8192 * 128 + tid] = 0u;  // sentinel
    }
}

// ---------------- fused scan + gather: one block per (batch,token) row ----
__global__ __launch_bounds__(256) void k_scanG(const float* __restrict__ qx,
                                               const float* __restrict__ px,
                                               const unsigned* __restrict__ wtp,
                                               unsigned* __restrict__ masks,
                                               unsigned* __restrict__ xbufu) {
    int row = blockIdx.x;              // 0..4607
    int b = row >> 4;
    const float* x = (b < NBQ) ? (qx + (size_t)row * CIN)
                               : (px + (size_t)(row - NBQ * LTOK) * CIN);
    __shared__ int idxs[200];
    __shared__ int cnt;
    __shared__ float sL[2][128], sH[2][128];
    int tid = threadIdx.x;
    if (tid == 0) cnt = 0;
    __syncthreads();
    const float4* x4 = (const float4*)x;
    float4 r[8];
#pragma unroll
    for (int j = 0; j < 8; ++j) r[j] = x4[j * 256 + tid];   // 8 outstanding loads
#pragma unroll
    for (int j = 0; j < 8; ++j) {
        unsigned ox = __float_as_uint(r[j].x) | __float_as_uint(r[j].y) |
                      __float_as_uint(r[j].z) | __float_as_uint(r[j].w);
        if (ox) {
            int base = (j * 256 + tid) * 4;
            float vv[4] = {r[j].x, r[j].y, r[j].z, r[j].w};
#pragma unroll
            for (int c = 0; c < 4; ++c) {
                if (vv[c] != 0.f) {
                    int k = base + c;
                    int p = atomicAdd(&cnt, 1);
                    if (p < 192) idxs[p] = k;
                    atomicOr(&masks[b * MASKW + (k >> 5)], 1u << (k & 31));
                }
            }
        }
    }
    __syncthreads();
    int n = min(cnt, 192);
    for (int i = n + tid; i < 200; i += 256) idxs[i] = 8192;   // sentinel pad
    __syncthreads();
    // gather: 128 channel-pairs x 2 j-halves
    int pair = tid & 127, half = tid >> 7;
    float aL = 0.f, aH = 0.f;
    for (int j0 = 0; j0 < n; j0 += 8) {
        int4 ia = *(const int4*)(idxs + j0 + half * 4);
        int id[4] = {ia.x, ia.y, ia.z, ia.w};
#pragma unroll
        for (int u = 0; u < 4; ++u) {
            unsigned v = wtp[(size_t)id[u] * 128 + pair];
            aL += __uint_as_float(v << 16);
            aH += __uint_as_float(v & 0xffff0000u);
        }
    }
    sL[half][pair] = aL; sH[half][pair] = aH;
    __syncthreads();
    if (tid < 128) {
        float L = sL[0][tid] + sL[1][tid];
        float H = sH[0][tid] + sH[1][tid];
        unsigned bl = f2bf(L), bh = f2bf(H);
        xbufu[(size_t)row * 128 + tid] = (bh << 16) | bl;
    }
}

// ---------------- conv layer GEMM (layers 1,2): 32 rows x 32 outs ---------
// Halo-only zero folded into the staging phase (no full-Als zero pass, one
// fewer barrier; MFMA reads never touch the un-zeroed pad columns).
__global__ __launch_bounds__(256) void k_cgemm(const unsigned short* __restrict__ actIn,
                                               unsigned short* __restrict__ actOut,
                                               const unsigned short* __restrict__ wl,
                                               const float* __restrict__ bias) {
    __shared__ unsigned short Als[2 * 20 * XROW];   // 21.1 KB
    __shared__ unsigned short Bls[32 * XROW];       // 16.9 KB
    int tid = threadIdx.x;
    int m0 = blockIdx.x * 32, n0 = blockIdx.y * 32;

    int row = tid >> 3, part = tid & 7;
    {
        const short8* src = (const short8*)(actIn + (size_t)(m0 + row) * 256 + part * 32);
        unsigned short* dst = Als + ((row >> 4) * 20 + (row & 15) + 2) * XROW + part * 32;
#pragma unroll
        for (int j = 0; j < 4; ++j) *(short8*)(dst + j * 8) = src[j];
    }
    // zero the 8 halo rows (2 strips x rows {0,1,18,19}); disjoint from staging
    if (tid < 132) {
        int* Az = (int*)Als;
#pragma unroll
        for (int pr = 0; pr < 8; ++pr) {
            const int rr[8] = {0, 1, 18, 19, 20, 21, 38, 39};
            Az[rr[pr] * 132 + tid] = 0;
        }
    }
    const unsigned short* bsrc = wl + (size_t)(n0 + row) * 1280 + part * 32;
    short8 rb[4];
#pragma unroll
    for (int j = 0; j < 4; ++j) rb[j] = *(const short8*)(bsrc + j * 8);

    int lane = tid & 63, wave = tid >> 6;
    int lane15 = lane & 15, quad = lane >> 4;
    int wm = wave & 1, wn = wave >> 1;
    unsigned short* bdst = Bls + row * XROW + part * 32;

    f32x4 acc = (f32x4){0.f, 0.f, 0.f, 0.f};
#pragma unroll 1
    for (int d = 0; d < 5; ++d) {
#pragma unroll
        for (int j = 0; j < 4; ++j) *(short8*)(bdst + j * 8) = rb[j];
        __syncthreads();
        if (d < 4) {
            const unsigned short* s2 = bsrc + (d + 1) * 256;
#pragma unroll
            for (int j = 0; j < 4; ++j) rb[j] = *(const short8*)(s2 + j * 8);
        }
        const unsigned short* ap = Als + (wm * 20 + lane15 + d) * XROW + quad * 8;
        const unsigned short* bp = Bls + (wn * 16 + lane15) * XROW + quad * 8;
#pragma unroll
        for (int kk = 0; kk < 8; ++kk) {
            short8 av = *(const short8*)(ap + kk * 32);
            short8 bv = *(const short8*)(bp + kk * 32);
            acc = __builtin_amdgcn_mfma_f32_16x16x32_bf16(av, bv, acc, 0, 0, 0);
        }
        __syncthreads();
    }

    int o = n0 + wn * 16 + lane15;
    float bv = bias[o];
    int rbase = m0 + wm * 16 + quad * 4;
#pragma unroll
    for (int r = 0; r < 4; ++r)
        actOut[(size_t)(rbase + r) * 256 + o] = f2bf(fmaxf(acc[r] + bv, 0.f));
}

// ---------------- conv layer 3 + fused mean/residual/relu + dec_w1 matvec --
__global__ __launch_bounds__(256) void k_cgemm3(const unsigned short* __restrict__ actIn,
                                                const unsigned short* __restrict__ wl,
                                                const float* __restrict__ bias,
                                                const unsigned short* __restrict__ xbuf,
                                                const float* __restrict__ dw1,
                                                float* __restrict__ Cmat) {
    __shared__ unsigned short Als[2 * 20 * XROW];
    __shared__ unsigned short Bls[32 * XROW];
    __shared__ float els[2][32];
    int tid = threadIdx.x;
    int m0 = blockIdx.x * 32, n0 = blockIdx.y * 32;

    int row = tid >> 3, part = tid & 7;
    {
        const short8* src = (const short8*)(actIn + (size_t)(m0 + row) * 256 + part * 32);
        unsigned short* dst = Als + ((row >> 4) * 20 + (row & 15) + 2) * XROW + part * 32;
#pragma unroll
        for (int j = 0; j < 4; ++j) *(short8*)(dst + j * 8) = src[j];
    }
    if (tid < 132) {
        int* Az = (int*)Als;
#pragma unroll
        for (int pr = 0; pr < 8; ++pr) {
            const int rr[8] = {0, 1, 18, 19, 20, 21, 38, 39};
            Az[rr[pr] * 132 + tid] = 0;
        }
    }
    const unsigned short* bsrc = wl + (size_t)(n0 + row) * 1280 + part * 32;
    short8 rb[4];
#pragma unroll
    for (int j = 0; j < 4; ++j) rb[j] = *(const short8*)(bsrc + j * 8);

    int lane = tid & 63, wave = tid >> 6;
    int lane15 = lane & 15, quad = lane >> 4;
    int wm = wave & 1, wn = wave >> 1;
    unsigned short* bdst = Bls + row * XROW + part * 32;

    f32x4 acc = (f32x4){0.f, 0.f, 0.f, 0.f};
#pragma unroll 1
    for (int d = 0; d < 5; ++d) {
#pragma unroll
        for (int j = 0; j < 4; ++j) *(short8*)(bdst + j * 8) = rb[j];
        __syncthreads();
        if (d < 4) {
            const unsigned short* s2 = bsrc + (d + 1) * 256;
#pragma unroll
            for (int j = 0; j < 4; ++j) rb[j] = *(const short8*)(s2 + j * 8);
        }
        const unsigned short* ap = Als + (wm * 20 + lane15 + d) * XROW + quad * 8;
        const unsigned short* bp = Bls + (wn * 16 + lane15) * XROW + quad * 8;
#pragma unroll
        for (int kk = 0; kk < 8; ++kk) {
            short8 av = *(const short8*)(ap + kk * 32);
            short8 bv = *(const short8*)(bp + kk * 32);
            acc = __builtin_amdgcn_mfma_f32_16x16x32_bf16(av, bv, acc, 0, 0, 0);
        }
        __syncthreads();
    }

    // token-mean of relu(conv3) + residual mean + relu -> e tile (2 batches x 32 outs)
    int o_l = wn * 16 + lane15;
    int o = n0 + o_l;
    float bv = bias[o];
    float sf = 0.f;
#pragma unroll
    for (int r = 0; r < 4; ++r) sf += fmaxf(acc[r] + bv, 0.f);
    sf += __shfl_xor(sf, 16, 64);
    sf += __shfl_xor(sf, 32, 64);
    if (quad == 0) {
        int bb = 2 * blockIdx.x + wm;
        float rs = 0.f;                 // residual: sum of 16 token row-sums from xbuf
#pragma unroll
        for (int t = 0; t < 16; ++t)
            rs += bf2f(xbuf[((size_t)bb * 16 + t) * 256 + o]);
        els[wm][o_l] = fmaxf((sf + rs) * (1.f / 16.f), 0.f);
    }
    __syncthreads();
    // partial Cmat[b][o'] += sum_{o in tile} dec_w1[o'][off + o] * e[b][o]
    if (tid < 64) {
        int b2 = tid >> 5, op = tid & 31;
        int bb = 2 * blockIdx.x + b2;
        const float* wr = dw1 + (size_t)op * 512 + (bb < NBQ ? 0 : 256) + n0;
        float s = 0.f;
#pragma unroll
        for (int j = 0; j < 32; ++j) s = fmaf(wr[j], els[b2][j], s);
        atomicAdd(&Cmat[bb * 32 + op], s);
    }
}

// ---------------- per-(q,p): tiny MLP + compacted sparse decode -----------
// compaction via wave-level shfl scan + 1 atomic/wave (was ~150 serialized
// same-address LDS atomics per block).
__global__ __launch_bounds__(256) void k_pair(const float* __restrict__ Cmat,
                                              const float* __restrict__ b1,
                                              const float* __restrict__ w2,
                                              const float* __restrict__ b2,
                                              const unsigned* __restrict__ w3p,
                                              const unsigned* __restrict__ masks,
                                              float* __restrict__ desc) {
    int p = blockIdx.x, q = blockIdx.y;
    __shared__ float h1[32];
    __shared__ __align__(16) float h2s[32];
    __shared__ int idxs[3072];
    __shared__ int cnt;
    __shared__ float wsum[4], wq[4];
    int tid = threadIdx.x;
    if (tid == 0) cnt = 0;
    __syncthreads();
    unsigned mq = masks[q * MASKW + tid];
    unsigned m = mq & masks[(NBQ + p) * MASKW + tid];
    int nb = __popc(m);
    {
        int lane = tid & 63;
        int inc = nb;                       // inclusive wave scan of popcounts
#pragma unroll
        for (int st = 1; st < 64; st <<= 1) {
            int v = __shfl_up(inc, st, 64);
            if (lane >= st) inc += v;
        }
        int wtot = __shfl(inc, 63, 64);
        int base0 = 0;
        if (lane == 63) base0 = atomicAdd(&cnt, wtot);
        base0 = __shfl(base0, 63, 64);
        int pos = base0 + inc - nb;
        while (m) {
            int bit = __ffs(m) - 1;
            m &= m - 1;
            idxs[pos++] = tid * 32 + bit;
        }
    }
    if (tid < 32)
        h1[tid] = fmaxf(Cmat[q * 32 + tid] + Cmat[(NBQ + p) * 32 + tid] + b1[tid], 0.f);
    __syncthreads();
    if (tid < 32) {
        float s = b2[tid];
#pragma unroll
        for (int j = 0; j < 32; ++j) s = fmaf(w2[tid * 32 + j], h1[j], s);
        h2s[tid] = fmaxf(s, 0.f);
    }
    __syncthreads();
    int n = cnt;
    int rowi = tid >> 2, part = tid & 3;          // 64 rows/iter, 4 lanes/row
    float h2v[8];
#pragma unroll
    for (int j = 0; j < 8; ++j) h2v[j] = h2s[part * 8 + j];
    float local = 0.f;
    for (int base = 0; base < n; base += 64) {
        int r = base + rowi;
        bool act = r < n;
        float dot = 0.f;
        if (act) {
            uint4 wv = *(const uint4*)(w3p + (size_t)idxs[r] * 16 + part * 4);
            unsigned wu[4] = {wv.x, wv.y, wv.z, wv.w};
#pragma unroll
            for (int u = 0; u < 4; ++u) {
                dot += __uint_as_float(wu[u] << 16) * h2v[2 * u];
                dot += __uint_as_float(wu[u] & 0xffff0000u) * h2v[2 * u + 1];
            }
        }
        dot += __shfl_xor(dot, 1);
        dot += __shfl_xor(dot, 2);
        if (act && part == 0)
            local += 1.f + (dot >= 0.f ? dot : dot * 0.125f);
    }
    float qcf = (float)__popc(mq);
#pragma unroll
    for (int st = 1; st < 64; st <<= 1) {
        local += __shfl_xor(local, st);
        qcf   += __shfl_xor(qcf, st);
    }
    if ((tid & 63) == 0) { wsum[tid >> 6] = local; wq[tid >> 6] = qcf; }
    __syncthreads();
    if (tid == 0) {
        float t  = wsum[0] + wsum[1] + wsum[2] + wsum[3];
        float qb = wq[0] + wq[1] + wq[2] + wq[3];
        desc[q * 256 + p] = t / qb;
    }
}

// ---------------- per-q: normalize over p + geo fusion --------------------
__global__ __launch_bounds__(256) void k_final(const float* __restrict__ desc,
                                               const float* __restrict__ qloc,
                                               const float* __restrict__ ploc,
                                               const float* __restrict__ sa,
                                               const float* __restrict__ sb,
                                               const float* __restrict__ sc,
                                               const float* __restrict__ sd,
                                               float* __restrict__ out) {
    __shared__ float red[256];
    int q = blockIdx.x, tid = threadIdx.x;
    float v = desc[q * 256 + tid];
    red[tid] = v; __syncthreads();
    for (int st = 128; st > 0; st >>= 1) {
        if (tid < st) red[tid] += red[tid + st];
        __syncthreads();
    }
    float mean = red[0] * (1.f / 256.f);
    __syncthreads();
    float dv = v - mean;
    red[tid] = dv * dv; __syncthreads();
    for (int st = 128; st > 0; st >>= 1) {
        if (tid < st) red[tid] += red[tid + st];
        __syncthreads();
    }
    float var = red[0] * (1.f / 255.f);
    float norm = dv / (sqrtf(var) + 1e-6f);
    float dx = qloc[q * 2]     - ploc[tid * 2];
    float dy = qloc[q * 2 + 1] - ploc[tid * 2 + 1];
    float dist = sqrtf(dx * dx + dy * dy);
    float z = sa[0] * norm + sb[0];
    float sig = 1.f / (1.f + expf(-z));
    out[q * 256 + tid] = (sc[0] - sig) * (-logf(dist + 1.f) - sd[0]);
}

extern "C" void kernel_launch(void* const* d_in, const int* in_sizes, int n_in,
                              void* d_out, int out_size, void* d_ws, size_t ws_size,
                              hipStream_t stream) {
    const float* qx   = (const float*)d_in[0];
    const float* qloc = (const float*)d_in[1];
    const float* px   = (const float*)d_in[2];
    const float* ploc = (const float*)d_in[3];
    const float* encw = (const float*)d_in[4];
    const float* cw1  = (const float*)d_in[5];
    const float* cb1  = (const float*)d_in[6];
    const float* cw2  = (const float*)d_in[7];
    const float* cb2  = (const float*)d_in[8];
    const float* cw3  = (const float*)d_in[9];
    const float* cb3  = (const float*)d_in[10];
    const float* dw1  = (const float*)d_in[11];
    const float* db1  = (const float*)d_in[12];
    const float* dw2  = (const float*)d_in[13];
    const float* db2  = (const float*)d_in[14];
    const float* dw3  = (const float*)d_in[15];
    const float* sa   = (const float*)d_in[16];
    const float* sb   = (const float*)d_in[17];
    const float* sc   = (const float*)d_in[18];
    const float* sd   = (const float*)d_in[19];

    char* w = (char*)d_ws;
    unsigned*       wtp   = (unsigned*)w;       w += (size_t)8193 * 128 * 4;      // 4.19 MB
    unsigned short* xbuf  = (unsigned short*)w; w += (size_t)NB * LTOK * H1 * 2;  // 2.25 MB
    unsigned short* act1  = (unsigned short*)w; w += (size_t)NB * LTOK * H1 * 2;
    unsigned short* act2  = (unsigned short*)w; w += (size_t)NB * LTOK * H1 * 2;
    unsigned short* wtb   = (unsigned short*)w; w += (size_t)3 * 256 * 1280 * 2;  // 1.97 MB
    unsigned*       w3p   = (unsigned*)w;       w += (size_t)CIN * 16 * 4;        // 512 KB
    float*          Cmat  = (float*)w;          w += (size_t)NB * H2 * 4;
    unsigned*       masks = (unsigned*)w;       w += (size_t)NB * MASKW * 4;
    float*          desc  = (float*)w;          w += (size_t)NBQ * NBP * 4;

    k_prep<<<6688, 256, 0, stream>>>(encw, cw1, cw2, cw3, dw3,
                                     wtp, wtb, w3p, masks, Cmat);
    k_scanG<<<NB * LTOK, 256, 0, stream>>>(qx, px, wtp, masks, (unsigned*)xbuf);
    dim3 cgrid(NB * LTOK / 32, 8);
    k_cgemm<<<cgrid, 256, 0, stream>>>(xbuf, act1, wtb,          cb1);
    k_cgemm<<<cgrid, 256, 0, stream>>>(act1, act2, wtb + 327680, cb2);
    k_cgemm3<<<cgrid, 256, 0, stream>>>(act2, wtb + 2 * 327680, cb3, xbuf, dw1, Cmat);
    k_pair<<<dim3(NBP, NBQ), 256, 0, stream>>>(Cmat, db1, dw2, db2, w3p, masks, desc);
    k_final<<<NBQ, 256, 0, stream>>>(desc, qloc, ploc, sa, sb, sc, sd, (float*)d_out);
}

// Round 9
// 323.415 us; speedup vs baseline: 1.2671x; 1.0100x over previous
//
#include <hip/hip_runtime.h>

#define NB 288          // 32 query + 256 poi batches
#define NBQ 32
#define NBP 256
#define LTOK 16
#define CIN 8192
#define H1 256
#define H2 32
#define MASKW 256       // 8192 bits / 32
#define XROW 264        // padded LDS row stride (bf16 elems)

typedef __attribute__((ext_vector_type(8))) short short8;   // 8 bf16 = 4 VGPRs
typedef __attribute__((ext_vector_type(4))) float f32x4;

__device__ __forceinline__ unsigned short f2bf(float f) {
    unsigned u = __float_as_uint(f);
    u += 0x7fffu + ((u >> 16) & 1u);
    return (unsigned short)(u >> 16);
}
__device__ __forceinline__ float bf2f(unsigned short u) {
    return __uint_as_float(((unsigned)u) << 16);
}

// ---------------- fused prep: enc_w transpose-pack, conv-w prep, w3 pack,
// ---------------- zero masks/Cmat + wtp sentinel row ----------------------
__global__ __launch_bounds__(256) void k_prep(const float* __restrict__ encw,
                                              const float* __restrict__ w1,
                                              const float* __restrict__ w2,
                                              const float* __restrict__ w3c,
                                              const float* __restrict__ dw3,
                                              unsigned* __restrict__ wtp,
                                              unsigned short* __restrict__ wtb,
                                              unsigned* __restrict__ w3p,
                                              unsigned* __restrict__ masks,
                                              float* __restrict__ Cmat) {
    int g = blockIdx.x, tid = threadIdx.x;
    if (g < 2048) {
        // enc_w (256,8192) fp32 -> wtp[k][pair] packed 2xbf16
        __shared__ float tile[32][33];
        int k0 = (g >> 3) * 32, h0 = (g & 7) * 32;
        int tx = tid & 31, ty = tid >> 5;
#pragma unroll
        for (int i = 0; i < 32; i += 8)
            tile[ty + i][tx] = encw[(h0 + ty + i) * CIN + k0 + tx];
        __syncthreads();
        int kl = tid >> 3, pw = tid & 7;
#pragma unroll
        for (int u = 0; u < 2; ++u) {
            int p = pw + u * 8;
            unsigned lo = f2bf(tile[2 * p][kl]);
            unsigned hi = f2bf(tile[2 * p + 1][kl]);
            wtp[(size_t)(k0 + kl) * 128 + (h0 >> 1) + p] = (hi << 16) | lo;
        }
    } else if (g < 5888) {
        // conv weights w[o][i][d] fp32 -> WT bf16 [l][o][d][i]
        int bx = g - 2048;
        int l = bx / 1280;
        int r = bx - l * 1280;
        int o = r / 5;
        int d = r - o * 5;
        const float* w = (l == 0) ? w1 : (l == 1) ? w2 : w3c;
        wtb[(size_t)l * 327680 + (size_t)o * 1280 + d * 256 + tid] =
            f2bf(w[(size_t)o * 1280 + tid * 5 + d]);
    } else if (g < 6400) {
        // dec_w3 (8192 x 32) fp32 -> w3p[k][16] packed bf16 pairs
        int idx = (g - 5888) * 256 + tid;
        int k = idx >> 4, pw = idx & 15;
        unsigned lo = f2bf(dw3[k * 32 + 2 * pw]);
        unsigned hi = f2bf(dw3[k * 32 + 2 * pw + 1]);
        w3p[idx] = (hi << 16) | lo;
    } else {
        int b = g - 6400;                 // 0..287
        masks[b * MASKW + tid] = 0u;
        if (tid < 32) Cmat[b * 32 + tid] = 0.f;
        if (b == 0 && tid < 128) wtp[(size_t)8192 * 128 + tid] = 0u;  // sentinel
    }
}

// ---------------- fused scan + gather: one block per (batch,token) row ----
// compaction via wave shfl-scan + 1 atomic/wave (was ~82 serialized
// same-address LDS atomics per block — pattern validated in k_pair, R8).
__global__ __launch_bounds__(256) void k_scanG(const float* __restrict__ qx,
                                               const float* __restrict__ px,
                                               const unsigned* __restrict__ wtp,
                                               unsigned* __restrict__ masks,
                                               unsigned* __restrict__ xbufu) {
    int row = blockIdx.x;              // 0..4607
    int b = row >> 4;
    const float* x = (b < NBQ) ? (qx + (size_t)row * CIN)
                               : (px + (size_t)(row - NBQ * LTOK) * CIN);
    __shared__ __align__(16) int idxs[200];
    __shared__ int cnt;
    __shared__ float sL[2][128], sH[2][128];
    int tid = threadIdx.x;
    if (tid == 0) cnt = 0;
    __syncthreads();
    const float4* x4 = (const float4*)x;
    float4 r[8];
#pragma unroll
    for (int j = 0; j < 8; ++j) r[j] = x4[j * 256 + tid];   // 8 outstanding loads

    // pass 1: per-thread nonzero count (registers already resident)
    int nb = 0;
#pragma unroll
    for (int j = 0; j < 8; ++j)
        nb += (r[j].x != 0.f) + (r[j].y != 0.f) + (r[j].z != 0.f) + (r[j].w != 0.f);
    // wave-inclusive scan + one atomic per wave
    int lane = tid & 63;
    int inc = nb;
#pragma unroll
    for (int st = 1; st < 64; st <<= 1) {
        int v = __shfl_up(inc, st, 64);
        if (lane >= st) inc += v;
    }
    int wtot = __shfl(inc, 63, 64);
    int base0 = 0;
    if (lane == 63) base0 = atomicAdd(&cnt, wtot);
    base0 = __shfl(base0, 63, 64);
    int pos = base0 + inc - nb;
    // pass 2: emit at deterministic positions + mask OR
#pragma unroll
    for (int j = 0; j < 8; ++j) {
        unsigned ox = __float_as_uint(r[j].x) | __float_as_uint(r[j].y) |
                      __float_as_uint(r[j].z) | __float_as_uint(r[j].w);
        if (ox) {
            int base = (j * 256 + tid) * 4;
            float vv[4] = {r[j].x, r[j].y, r[j].z, r[j].w};
#pragma unroll
            for (int c = 0; c < 4; ++c) {
                if (vv[c] != 0.f) {
                    int k = base + c;
                    if (pos < 192) idxs[pos] = k;
                    pos++;
                    atomicOr(&masks[b * MASKW + (k >> 5)], 1u << (k & 31));
                }
            }
        }
    }
    __syncthreads();
    int n = min(cnt, 192);
    for (int i = n + tid; i < 200; i += 256) idxs[i] = 8192;   // sentinel pad
    __syncthreads();
    // gather: 128 channel-pairs x 2 j-halves
    int pair = tid & 127, half = tid >> 7;
    float aL = 0.f, aH = 0.f;
    for (int j0 = 0; j0 < n; j0 += 8) {
        int4 ia = *(const int4*)(idxs + j0 + half * 4);
        int id[4] = {ia.x, ia.y, ia.z, ia.w};
#pragma unroll
        for (int u = 0; u < 4; ++u) {
            unsigned v = wtp[(size_t)id[u] * 128 + pair];
            aL += __uint_as_float(v << 16);
            aH += __uint_as_float(v & 0xffff0000u);
        }
    }
    sL[half][pair] = aL; sH[half][pair] = aH;
    __syncthreads();
    if (tid < 128) {
        float L = sL[0][tid] + sL[1][tid];
        float H = sH[0][tid] + sH[1][tid];
        unsigned bl = f2bf(L), bh = f2bf(H);
        xbufu[(size_t)row * 128 + tid] = (bh << 16) | bl;
    }
}

// ---------------- conv layer GEMM (layers 1,2): 32 rows x 32 outs ---------
// Halo-only zero folded into the staging phase (no full-Als zero pass, one
// fewer barrier; MFMA reads never touch the un-zeroed pad columns).
__global__ __launch_bounds__(256) void k_cgemm(const unsigned short* __restrict__ actIn,
                                               unsigned short* __restrict__ actOut,
                                               const unsigned short* __restrict__ wl,
                                               const float* __restrict__ bias) {
    __shared__ unsigned short Als[2 * 20 * XROW];   // 21.1 KB
    __shared__ unsigned short Bls[32 * XROW];       // 16.9 KB
    int tid = threadIdx.x;
    int m0 = blockIdx.x * 32, n0 = blockIdx.y * 32;

    int row = tid >> 3, part = tid & 7;
    {
        const short8* src = (const short8*)(actIn + (size_t)(m0 + row) * 256 + part * 32);
        unsigned short* dst = Als + ((row >> 4) * 20 + (row & 15) + 2) * XROW + part * 32;
#pragma unroll
        for (int j = 0; j < 4; ++j) *(short8*)(dst + j * 8) = src[j];
    }
    // zero the 8 halo rows (2 strips x rows {0,1,18,19}); disjoint from staging
    if (tid < 132) {
        int* Az = (int*)Als;
#pragma unroll
        for (int pr = 0; pr < 8; ++pr) {
            const int rr[8] = {0, 1, 18, 19, 20, 21, 38, 39};
            Az[rr[pr] * 132 + tid] = 0;
        }
    }
    const unsigned short* bsrc = wl + (size_t)(n0 + row) * 1280 + part * 32;
    short8 rb[4];
#pragma unroll
    for (int j = 0; j < 4; ++j) rb[j] = *(const short8*)(bsrc + j * 8);

    int lane = tid & 63, wave = tid >> 6;
    int lane15 = lane & 15, quad = lane >> 4;
    int wm = wave & 1, wn = wave >> 1;
    unsigned short* bdst = Bls + row * XROW + part * 32;

    f32x4 acc = (f32x4){0.f, 0.f, 0.f, 0.f};
#pragma unroll 1
    for (int d = 0; d < 5; ++d) {
#pragma unroll
        for (int j = 0; j < 4; ++j) *(short8*)(bdst + j * 8) = rb[j];
        __syncthreads();
        if (d < 4) {
            const unsigned short* s2 = bsrc + (d + 1) * 256;
#pragma unroll
            for (int j = 0; j < 4; ++j) rb[j] = *(const short8*)(s2 + j * 8);
        }
        const unsigned short* ap = Als + (wm * 20 + lane15 + d) * XROW + quad * 8;
        const unsigned short* bp = Bls + (wn * 16 + lane15) * XROW + quad * 8;
#pragma unroll
        for (int kk = 0; kk < 8; ++kk) {
            short8 av = *(const short8*)(ap + kk * 32);
            short8 bv = *(const short8*)(bp + kk * 32);
            acc = __builtin_amdgcn_mfma_f32_16x16x32_bf16(av, bv, acc, 0, 0, 0);
        }
        __syncthreads();
    }

    int o = n0 + wn * 16 + lane15;
    float bv = bias[o];
    int rbase = m0 + wm * 16 + quad * 4;
#pragma unroll
    for (int r = 0; r < 4; ++r)
        actOut[(size_t)(rbase + r) * 256 + o] = f2bf(fmaxf(acc[r] + bv, 0.f));
}

// ---------------- conv layer 3 + fused mean/residual/relu + dec_w1 matvec --
__global__ __launch_bounds__(256) void k_cgemm3(const unsigned short* __restrict__ actIn,
                                                const unsigned short* __restrict__ wl,
                                                const float* __restrict__ bias,
                                                const unsigned short* __restrict__ xbuf,
                                                const float* __restrict__ dw1,
                                                float* __restrict__ Cmat) {
    __shared__ unsigned short Als[2 * 20 * XROW];
    __shared__ unsigned short Bls[32 * XROW];
    __shared__ float els[2][32];
    int tid = threadIdx.x;
    int m0 = blockIdx.x * 32, n0 = blockIdx.y * 32;

    int row = tid >> 3, part = tid & 7;
    {
        const short8* src = (const short8*)(actIn + (size_t)(m0 + row) * 256 + part * 32);
        unsigned short* dst = Als + ((row >> 4) * 20 + (row & 15) + 2) * XROW + part * 32;
#pragma unroll
        for (int j = 0; j < 4; ++j) *(short8*)(dst + j * 8) = src[j];
    }
    if (tid < 132) {
        int* Az = (int*)Als;
#pragma unroll
        for (int pr = 0; pr < 8; ++pr) {
            const int rr[8] = {0, 1, 18, 19, 20, 21, 38, 39};
            Az[rr[pr] * 132 + tid] = 0;
        }
    }
    const unsigned short* bsrc = wl + (size_t)(n0 + row) * 1280 + part * 32;
    short8 rb[4];
#pragma unroll
    for (int j = 0; j < 4; ++j) rb[j] = *(const short8*)(bsrc + j * 8);

    int lane = tid & 63, wave = tid >> 6;
    int lane15 = lane & 15, quad = lane >> 4;
    int wm = wave & 1, wn = wave >> 1;
    unsigned short* bdst = Bls + row * XROW + part * 32;

    f32x4 acc = (f32x4){0.f, 0.f, 0.f, 0.f};
#pragma unroll 1
    for (int d = 0; d < 5; ++d) {
#pragma unroll
        for (int j = 0; j < 4; ++j) *(short8*)(bdst + j * 8) = rb[j];
        __syncthreads();
        if (d < 4) {
            const unsigned short* s2 = bsrc + (d + 1) * 256;
#pragma unroll
            for (int j = 0; j < 4; ++j) rb[j] = *(const short8*)(s2 + j * 8);
        }
        const unsigned short* ap = Als + (wm * 20 + lane15 + d) * XROW + quad * 8;
        const unsigned short* bp = Bls + (wn * 16 + lane15) * XROW + quad * 8;
#pragma unroll
        for (int kk = 0; kk < 8; ++kk) {
            short8 av = *(const short8*)(ap + kk * 32);
            short8 bv = *(const short8*)(bp + kk * 32);
            acc = __builtin_amdgcn_mfma_f32_16x16x32_bf16(av, bv, acc, 0, 0, 0);
        }
        __syncthreads();
    }

    // token-mean of relu(conv3) + residual mean + relu -> e tile (2 batches x 32 outs)
    int o_l = wn * 16 + lane15;
    int o = n0 + o_l;
    float bv = bias[o];
    float sf = 0.f;
#pragma unroll
    for (int r = 0; r < 4; ++r) sf += fmaxf(acc[r] + bv, 0.f);
    sf += __shfl_xor(sf, 16, 64);
    sf += __shfl_xor(sf, 32, 64);
    if (quad == 0) {
        int bb = 2 * blockIdx.x + wm;
        float rs = 0.f;                 // residual: sum of 16 token row-sums from xbuf
#pragma unroll
        for (int t = 0; t < 16; ++t)
            rs += bf2f(xbuf[((size_t)bb * 16 + t) * 256 + o]);
        els[wm][o_l] = fmaxf((sf + rs) * (1.f / 16.f), 0.f);
    }
    __syncthreads();
    // partial Cmat[b][o'] += sum_{o in tile} dec_w1[o'][off + o] * e[b][o]
    if (tid < 64) {
        int b2 = tid >> 5, op = tid & 31;
        int bb = 2 * blockIdx.x + b2;
        const float* wr = dw1 + (size_t)op * 512 + (bb < NBQ ? 0 : 256) + n0;
        float s = 0.f;
#pragma unroll
        for (int j = 0; j < 32; ++j) s = fmaf(wr[j], els[b2][j], s);
        atomicAdd(&Cmat[bb * 32 + op], s);
    }
}

// ---------------- per-(q,p): tiny MLP + compacted sparse decode -----------
// compaction via wave-level shfl scan + 1 atomic/wave (validated R8).
__global__ __launch_bounds__(256) void k_pair(const float* __restrict__ Cmat,
                                              const float* __restrict__ b1,
                                              const float* __restrict__ w2,
                                              const float* __restrict__ b2,
                                              const unsigned* __restrict__ w3p,
                                              const unsigned* __restrict__ masks,
                                              float* __restrict__ desc) {
    int p = blockIdx.x, q = blockIdx.y;
    __shared__ float h1[32];
    __shared__ __align__(16) float h2s[32];
    __shared__ int idxs[3072];
    __shared__ int cnt;
    __shared__ float wsum[4], wq[4];
    int tid = threadIdx.x;
    if (tid == 0) cnt = 0;
    __syncthreads();
    unsigned mq = masks[q * MASKW + tid];
    unsigned m = mq & masks[(NBQ + p) * MASKW + tid];
    int nb = __popc(m);
    {
        int lane = tid & 63;
        int inc = nb;                       // inclusive wave scan of popcounts
#pragma unroll
        for (int st = 1; st < 64; st <<= 1) {
            int v = __shfl_up(inc, st, 64);
            if (lane >= st) inc += v;
        }
        int wtot = __shfl(inc, 63, 64);
        int base0 = 0;
        if (lane == 63) base0 = atomicAdd(&cnt, wtot);
        base0 = __shfl(base0, 63, 64);
        int pos = base0 + inc - nb;
        while (m) {
            int bit = __ffs(m) - 1;
            m &= m - 1;
            idxs[pos++] = tid * 32 + bit;
        }
    }
    if (tid < 32)
        h1[tid] = fmaxf(Cmat[q * 32 + tid] + Cmat[(NBQ + p) * 32 + tid] + b1[tid], 0.f);
    __syncthreads();
    if (tid < 32) {
        float s = b2[tid];
#pragma unroll
        for (int j = 0; j < 32; ++j) s = fmaf(w2[tid * 32 + j], h1[j], s);
        h2s[tid] = fmaxf(s, 0.f);
    }
    __syncthreads();
    int n = cnt;
    int rowi = tid >> 2, part = tid & 3;          // 64 rows/iter, 4 lanes/row
    float h2v[8];
#pragma unroll
    for (int j = 0; j < 8; ++j) h2v[j] = h2s[part * 8 + j];
    float local = 0.f;
    for (int base = 0; base < n; base += 64) {
        int r = base + rowi;
        bool act = r < n;
        float dot = 0.f;
        if (act) {
            uint4 wv = *(const uint4*)(w3p + (size_t)idxs[r] * 16 + part * 4);
            unsigned wu[4] = {wv.x, wv.y, wv.z, wv.w};
#pragma unroll
            for (int u = 0; u < 4; ++u) {
                dot += __uint_as_float(wu[u] << 16) * h2v[2 * u];
                dot += __uint_as_float(wu[u] & 0xffff0000u) * h2v[2 * u + 1];
            }
        }
        dot += __shfl_xor(dot, 1);
        dot += __shfl_xor(dot, 2);
        if (act && part == 0)
            local += 1.f + (dot >= 0.f ? dot : dot * 0.125f);
    }
    float qcf = (float)__popc(mq);
#pragma unroll
    for (int st = 1; st < 64; st <<= 1) {
        local += __shfl_xor(local, st);
        qcf   += __shfl_xor(qcf, st);
    }
    if ((tid & 63) == 0) { wsum[tid >> 6] = local; wq[tid >> 6] = qcf; }
    __syncthreads();
    if (tid == 0) {
        float t  = wsum[0] + wsum[1] + wsum[2] + wsum[3];
        float qb = wq[0] + wq[1] + wq[2] + wq[3];
        desc[q * 256 + p] = t / qb;
    }
}

// ---------------- per-q: normalize over p + geo fusion --------------------
__global__ __launch_bounds__(256) void k_final(const float* __restrict__ desc,
                                               const float* __restrict__ qloc,
                                               const float* __restrict__ ploc,
                                               const float* __restrict__ sa,
                                               const float* __restrict__ sb,
                                               const float* __restrict__ sc,
                                               const float* __restrict__ sd,
                                               float* __restrict__ out) {
    __shared__ float red[256];
    int q = blockIdx.x, tid = threadIdx.x;
    float v = desc[q * 256 + tid];
    red[tid] = v; __syncthreads();
    for (int st = 128; st > 0; st >>= 1) {
        if (tid < st) red[tid] += red[tid + st];
        __syncthreads();
    }
    float mean = red[0] * (1.f / 256.f);
    __syncthreads();
    float dv = v - mean;
    red[tid] = dv * dv; __syncthreads();
    for (int st = 128; st > 0; st >>= 1) {
        if (tid < st) red[tid] += red[tid + st];
        __syncthreads();
    }
    float var = red[0] * (1.f / 255.f);
    float norm = dv / (sqrtf(var) + 1e-6f);
    float dx = qloc[q * 2]     - ploc[tid * 2];
    float dy = qloc[q * 2 + 1] - ploc[tid * 2 + 1];
    float dist = sqrtf(dx * dx + dy * dy);
    float z = sa[0] * norm + sb[0];
    float sig = 1.f / (1.f + expf(-z));
    out[q * 256 + tid] = (sc[0] - sig) * (-logf(dist + 1.f) - sd[0]);
}

extern "C" void kernel_launch(void* const* d_in, const int* in_sizes, int n_in,
                              void* d_out, int out_size, void* d_ws, size_t ws_size,
                              hipStream_t stream) {
    const float* qx   = (const float*)d_in[0];
    const float* qloc = (const float*)d_in[1];
    const float* px   = (const float*)d_in[2];
    const float* ploc = (const float*)d_in[3];
    const float* encw = (const float*)d_in[4];
    const float* cw1  = (const float*)d_in[5];
    const float* cb1  = (const float*)d_in[6];
    const float* cw2  = (const float*)d_in[7];
    const float* cb2  = (const float*)d_in[8];
    const float* cw3  = (const float*)d_in[9];
    const float* cb3  = (const float*)d_in[10];
    const float* dw1  = (const float*)d_in[11];
    const float* db1  = (const float*)d_in[12];
    const float* dw2  = (const float*)d_in[13];
    const float* db2  = (const float*)d_in[14];
    const float* dw3  = (const float*)d_in[15];
    const float* sa   = (const float*)d_in[16];
    const float* sb   = (const float*)d_in[17];
    const float* sc   = (const float*)d_in[18];
    const float* sd   = (const float*)d_in[19];

    char* w = (char*)d_ws;
    unsigned*       wtp   = (unsigned*)w;       w += (size_t)8193 * 128 * 4;      // 4.19 MB
    unsigned short* xbuf  = (unsigned short*)w; w += (size_t)NB * LTOK * H1 * 2;  // 2.25 MB
    unsigned short* act1  = (unsigned short*)w; w += (size_t)NB * LTOK * H1 * 2;
    unsigned short* act2  = (unsigned short*)w; w += (size_t)NB * LTOK * H1 * 2;
    unsigned short* wtb   = (unsigned short*)w; w += (size_t)3 * 256 * 1280 * 2;  // 1.97 MB
    unsigned*       w3p   = (unsigned*)w;       w += (size_t)CIN * 16 * 4;        // 512 KB
    float*          Cmat  = (float*)w;          w += (size_t)NB * H2 * 4;
    unsigned*       masks = (unsigned*)w;       w += (size_t)NB * MASKW * 4;
    float*          desc  = (float*)w;          w += (size_t)NBQ * NBP * 4;

    k_prep<<<6688, 256, 0, stream>>>(encw, cw1, cw2, cw3, dw3,
                                     wtp, wtb, w3p, masks, Cmat);
    k_scanG<<<NB * LTOK, 256, 0, stream>>>(qx, px, wtp, masks, (unsigned*)xbuf);
    dim3 cgrid(NB * LTOK / 32, 8);
    k_cgemm<<<cgrid, 256, 0, stream>>>(xbuf, act1, wtb,          cb1);
    k_cgemm<<<cgrid, 256, 0, stream>>>(act1, act2, wtb + 327680, cb2);
    k_cgemm3<<<cgrid, 256, 0, stream>>>(act2, wtb + 2 * 327680, cb3, xbuf, dw1, Cmat);
    k_pair<<<dim3(NBP, NBQ), 256, 0, stream>>>(Cmat, db1, dw2, db2, w3p, masks, desc);
    k_final<<<NBQ, 256, 0, stream>>>(desc, qloc, ploc, sa, sb, sc, sd, (float*)d_out);
}